// Round 8
// baseline (266.689 us; speedup 1.0000x reference)
//
#include <hip/hip_runtime.h>
#include <cstddef>

#define L_SEQ 32768
#define H_FEAT 512
#define P_STATE 256
#define N2 512              // 2*P (re/im interleaved)
#define CS 32               // scan chunk size
#define NCH (L_SEQ / CS)    // 1024 chunks

typedef __bf16 bf16x8 __attribute__((ext_vector_type(8)));
typedef float f32x4 __attribute__((ext_vector_type(4)));

// async global->LDS, 16B per lane; LDS dst must be uniform base + lane*16
#define GLDS16(g, l) __builtin_amdgcn_global_load_lds( \
    (const __attribute__((address_space(1))) void*)(g), \
    (__attribute__((address_space(3))) void*)(l), 16, 0, 0)

__device__ __forceinline__ unsigned bf_rne(float x) {   // bf16 bits (RNE) in low 16
    unsigned u = __float_as_uint(x);
    return (u + 0x7fffu + ((u >> 16) & 1u)) >> 16;
}
__device__ __forceinline__ float bf_f(unsigned bits) {
    return __uint_as_float(bits << 16);
}
__device__ __forceinline__ float2 cmul(float2 a, float2 b) {
    return make_float2(a.x * b.x - a.y * b.y, a.x * b.y + a.y * b.x);
}

// ---------------------------------------------------------------------------
// Params: W split (bf16 hi/lo, [N2][H]), C2 split ([H][N2]), Abar,
// Apw[r][p] = Abar_p^(r+1) for r=0..CS-1 (carry-application table).
// ---------------------------------------------------------------------------
__global__ __launch_bounds__(256) void param_kernel(
    const float* __restrict__ lr, const float* __restrict__ li,
    const float* __restrict__ b,  const float* __restrict__ c,
    const float* __restrict__ delta,
    ushort* __restrict__ W_hi, ushort* __restrict__ W_lo,
    ushort* __restrict__ C2_hi, ushort* __restrict__ C2_lo,
    float2* __restrict__ Abar, float2* __restrict__ Apw)
{
    int tid = blockIdx.x * blockDim.x + threadIdx.x;   // 0 .. P*H-1 (131072)

    {
        int p = tid >> 9;
        int h = tid & 511;
        float step = expf(delta[p]);
        float zr = 0.5f * step * lr[p];
        float zi = 0.5f * step * li[p];
        float dr = 1.0f - zr, di = -zi;
        float den = dr * dr + di * di;
        float blr = dr / den, bli = -di / den;       // BL = 1/(1-z)
        float bbr = blr * step, bbi = bli * step;    // BL*step
        float b0 = b[((size_t)(p * H_FEAT + h)) * 2 + 0];
        float b1 = b[((size_t)(p * H_FEAT + h)) * 2 + 1];
        float vr = bbr * b0 - bbi * b1;              // Re(B_bar)
        float vi = bbr * b1 + bbi * b0;              // Im(B_bar)
        unsigned hr = bf_rne(vr), hl = bf_rne(vr - bf_f(hr));
        unsigned ir = bf_rne(vi), il = bf_rne(vi - bf_f(ir));
        size_t o0 = (size_t)(2 * p) * H_FEAT + h;
        size_t o1 = (size_t)(2 * p + 1) * H_FEAT + h;
        W_hi[o0] = (ushort)hr; W_lo[o0] = (ushort)hl;
        W_hi[o1] = (ushort)ir; W_lo[o1] = (ushort)il;
    }

    {
        int h2 = tid >> 8;
        int p2 = tid & 255;
        float c0 =  2.0f * c[((size_t)(h2 * P_STATE + p2)) * 2 + 0];
        float c1 = -2.0f * c[((size_t)(h2 * P_STATE + p2)) * 2 + 1];
        unsigned h0 = bf_rne(c0), l0 = bf_rne(c0 - bf_f(h0));
        unsigned h1 = bf_rne(c1), l1 = bf_rne(c1 - bf_f(h1));
        size_t o0 = (size_t)h2 * N2 + 2 * p2;
        C2_hi[o0] = (ushort)h0;     C2_lo[o0] = (ushort)l0;
        C2_hi[o0 + 1] = (ushort)h1; C2_lo[o0 + 1] = (ushort)l1;
    }

    // Abar and power table: tid < CS*P (8192); r = tid>>8, p = tid&255
    if (tid < CS * P_STATE) {
        int r = tid >> 8;
        int p = tid & 255;
        float step = expf(delta[p]);
        float zr = 0.5f * step * lr[p];
        float zi = 0.5f * step * li[p];
        float dr = 1.0f - zr, di = -zi;
        float den = dr * dr + di * di;
        float blr = dr / den, bli = -di / den;
        float nr = 1.0f + zr, ni = zi;
        float2 ab = make_float2(blr * nr - bli * ni, blr * ni + bli * nr);
        if (r == 0) Abar[p] = ab;
        // Apw[r][p] = ab^(r+1), binary exponentiation
        int e = r + 1;
        float2 res = make_float2(1.f, 0.f), base = ab;
        while (e) {
            if (e & 1) res = cmul(res, base);
            base = cmul(base, base);
            e >>= 1;
        }
        Apw[r * P_STATE + p] = res;
    }
}

// ---------------------------------------------------------------------------
// GEMM1: Bu[M][512] = u[M][512](f32, split during staging) @ W[512][512]^T
// BM=128, BN=256, BK=32, 256 threads (4 waves), wave tile 64x128 (4x8 frags),
// 3 MFMA per frag. grid = (2, 256).   [round-3 proven config]
// ---------------------------------------------------------------------------
__global__ __launch_bounds__(256, 2) void gemm1(
    const float* __restrict__ A,
    const ushort* __restrict__ Bhi, const ushort* __restrict__ Blo,
    float* __restrict__ C)
{
    __shared__ ushort As_hi[128 * 32], As_lo[128 * 32];
    __shared__ ushort Bs_hi[256 * 32], Bs_lo[256 * 32];
    const int tid = threadIdx.x;
    const int ln = tid & 63, wv = tid >> 6;
    const int bm = blockIdx.y * 128, bn = blockIdx.x * 256;
    const int m = ln & 15, q = ln >> 4;
    const int wr = (wv >> 1) * 64, wc = (wv & 1) * 128;

    f32x4 acc[4][8] = {};

    for (int k0 = 0; k0 < 512; k0 += 32) {
#pragma unroll
        for (int s = 0; s < 8; s++) {
            int t = wv * 8 + s;            // 0..31
            int ch = t & 15;
            int row = ch * 16 + (ln >> 2);
            const ushort* src = (t < 16 ? Bhi : Blo)
                                + (size_t)(bn + row) * 512 + k0 + (ln & 3) * 8;
            ushort* dst = (t < 16 ? Bs_hi : Bs_lo) + ch * 512 + ln * 8;
            GLDS16(src, dst);
        }
#pragma unroll
        for (int r = 0; r < 4; r++) {
            int idx = tid + r * 256;       // 0..1023
            int row = idx >> 3;
            int c4 = (idx & 7) << 2;
            const float4 v = *(const float4*)(A + (size_t)(bm + row) * 512 + k0 + c4);
            unsigned u0 = __float_as_uint(v.x), u1 = __float_as_uint(v.y);
            unsigned u2 = __float_as_uint(v.z), u3 = __float_as_uint(v.w);
            unsigned hi01 = (u0 >> 16) | (u1 & 0xffff0000u);
            unsigned hi23 = (u2 >> 16) | (u3 & 0xffff0000u);
            float d0 = v.x - __uint_as_float(u0 & 0xffff0000u);
            float d1 = v.y - __uint_as_float(u1 & 0xffff0000u);
            float d2 = v.z - __uint_as_float(u2 & 0xffff0000u);
            float d3 = v.w - __uint_as_float(u3 & 0xffff0000u);
            unsigned lo01 = (__float_as_uint(d0) >> 16) | (__float_as_uint(d1) & 0xffff0000u);
            unsigned lo23 = (__float_as_uint(d2) >> 16) | (__float_as_uint(d3) & 0xffff0000u);
            *(uint2*)(As_hi + row * 32 + c4) = make_uint2(hi01, hi23);
            *(uint2*)(As_lo + row * 32 + c4) = make_uint2(lo01, lo23);
        }
        __syncthreads();

        bf16x8 ah[4], al[4];
#pragma unroll
        for (int i = 0; i < 4; i++) {
            ah[i] = *(const bf16x8*)(As_hi + (wr + i * 16 + m) * 32 + q * 8);
            al[i] = *(const bf16x8*)(As_lo + (wr + i * 16 + m) * 32 + q * 8);
        }
#pragma unroll
        for (int j = 0; j < 8; j++) {
            bf16x8 bh = *(const bf16x8*)(Bs_hi + (wc + j * 16 + m) * 32 + q * 8);
            bf16x8 bl = *(const bf16x8*)(Bs_lo + (wc + j * 16 + m) * 32 + q * 8);
#pragma unroll
            for (int i = 0; i < 4; i++)
                acc[i][j] = __builtin_amdgcn_mfma_f32_16x16x32_bf16(ah[i], bh, acc[i][j], 0, 0, 0);
#pragma unroll
            for (int i = 0; i < 4; i++)
                acc[i][j] = __builtin_amdgcn_mfma_f32_16x16x32_bf16(al[i], bh, acc[i][j], 0, 0, 0);
#pragma unroll
            for (int i = 0; i < 4; i++)
                acc[i][j] = __builtin_amdgcn_mfma_f32_16x16x32_bf16(ah[i], bl, acc[i][j], 0, 0, 0);
        }
        __syncthreads();
    }

#pragma unroll
    for (int i = 0; i < 4; i++)
#pragma unroll
        for (int j = 0; j < 8; j++)
#pragma unroll
            for (int r = 0; r < 4; r++) {
                int row = bm + wr + i * 16 + q * 4 + r;
                int col = bn + wc + j * 16 + m;
                C[(size_t)row * 512 + col] = acc[i][j][r];
            }
}

// ---------------------------------------------------------------------------
// GEMM2: out[M][512] = xs @ C2^T + d*u, where xs is reconstructed on the fly:
// xs[l][p] = s_loc[l][p] + Abar_p^((l%CS)+1) * carry[l/CS][p], then split to
// bf16 hi/lo during staging (same split as gemm1).
// ---------------------------------------------------------------------------
__global__ __launch_bounds__(256, 2) void gemm2(
    const float* __restrict__ Xs,          // s_loc, f32 [L][512]
    const float2* __restrict__ Apw,        // [CS][256]
    const float2* __restrict__ carr,       // [NCH][256]
    const ushort* __restrict__ Bhi, const ushort* __restrict__ Blo,
    float* __restrict__ Cout, const float* __restrict__ U,
    const float* __restrict__ dvec)
{
    __shared__ ushort As_hi[128 * 32], As_lo[128 * 32];
    __shared__ ushort Bs_hi[256 * 32], Bs_lo[256 * 32];
    __shared__ __align__(16) float cLds[4 * 512];   // 4 chunks x 256 float2
    const int tid = threadIdx.x;
    const int ln = tid & 63, wv = tid >> 6;
    const int bm = blockIdx.y * 128, bn = blockIdx.x * 256;
    const int m = ln & 15, q = ln >> 4;
    const int wr = (wv >> 1) * 64, wc = (wv & 1) * 128;

    // preload the block's 4 chunk-carries (rows bm..bm+127 -> chunks bm/32+0..3)
    if (tid < 256) {
#pragma unroll
        for (int k = 0; k < 4; k++) {
            float2 cv = carr[(size_t)(blockIdx.y * 4 + k) * P_STATE + tid];
            ((float2*)cLds)[k * 256 + tid] = cv;
        }
    }
    __syncthreads();

    f32x4 acc[4][8] = {};

    for (int k0 = 0; k0 < 512; k0 += 32) {
#pragma unroll
        for (int s = 0; s < 8; s++) {
            int t = wv * 8 + s;
            int ch = t & 15;
            int row = ch * 16 + (ln >> 2);
            const ushort* src = (t < 16 ? Bhi : Blo)
                                + (size_t)(bn + row) * 512 + k0 + (ln & 3) * 8;
            ushort* dst = (t < 16 ? Bs_hi : Bs_lo) + ch * 512 + ln * 8;
            GLDS16(src, dst);
        }
#pragma unroll
        for (int r = 0; r < 4; r++) {
            int idx = tid + r * 256;
            int row = idx >> 3;            // block-local row 0..127
            int c4 = (idx & 7) << 2;
            const float4 v = *(const float4*)(Xs + (size_t)(bm + row) * 512 + k0 + c4);
            int p0 = (k0 + c4) >> 1;       // even
            const float4 w = *(const float4*)(Apw + (size_t)(row & 31) * P_STATE + p0);
            const float4 cv = *(const float4*)(cLds + (row >> 5) * 512 + 2 * p0);
            // x = s_loc + A^(off+1) * carry  (complex, 2 p's)
            float x0 = fmaf(w.x, cv.x, fmaf(-w.y, cv.y, v.x));
            float y0 = fmaf(w.x, cv.y, fmaf(w.y, cv.x, v.y));
            float x1 = fmaf(w.z, cv.z, fmaf(-w.w, cv.w, v.z));
            float y1 = fmaf(w.z, cv.w, fmaf(w.w, cv.z, v.w));
            unsigned u0 = __float_as_uint(x0), u1 = __float_as_uint(y0);
            unsigned u2 = __float_as_uint(x1), u3 = __float_as_uint(y1);
            unsigned hi01 = (u0 >> 16) | (u1 & 0xffff0000u);
            unsigned hi23 = (u2 >> 16) | (u3 & 0xffff0000u);
            float d0 = x0 - __uint_as_float(u0 & 0xffff0000u);
            float d1 = y0 - __uint_as_float(u1 & 0xffff0000u);
            float d2 = x1 - __uint_as_float(u2 & 0xffff0000u);
            float d3 = y1 - __uint_as_float(u3 & 0xffff0000u);
            unsigned lo01 = (__float_as_uint(d0) >> 16) | (__float_as_uint(d1) & 0xffff0000u);
            unsigned lo23 = (__float_as_uint(d2) >> 16) | (__float_as_uint(d3) & 0xffff0000u);
            *(uint2*)(As_hi + row * 32 + c4) = make_uint2(hi01, hi23);
            *(uint2*)(As_lo + row * 32 + c4) = make_uint2(lo01, lo23);
        }
        __syncthreads();

        bf16x8 ah[4], al[4];
#pragma unroll
        for (int i = 0; i < 4; i++) {
            ah[i] = *(const bf16x8*)(As_hi + (wr + i * 16 + m) * 32 + q * 8);
            al[i] = *(const bf16x8*)(As_lo + (wr + i * 16 + m) * 32 + q * 8);
        }
#pragma unroll
        for (int j = 0; j < 8; j++) {
            bf16x8 bh = *(const bf16x8*)(Bs_hi + (wc + j * 16 + m) * 32 + q * 8);
            bf16x8 bl = *(const bf16x8*)(Bs_lo + (wc + j * 16 + m) * 32 + q * 8);
#pragma unroll
            for (int i = 0; i < 4; i++)
                acc[i][j] = __builtin_amdgcn_mfma_f32_16x16x32_bf16(ah[i], bh, acc[i][j], 0, 0, 0);
#pragma unroll
            for (int i = 0; i < 4; i++)
                acc[i][j] = __builtin_amdgcn_mfma_f32_16x16x32_bf16(al[i], bh, acc[i][j], 0, 0, 0);
#pragma unroll
            for (int i = 0; i < 4; i++)
                acc[i][j] = __builtin_amdgcn_mfma_f32_16x16x32_bf16(ah[i], bl, acc[i][j], 0, 0, 0);
        }
        __syncthreads();
    }

#pragma unroll
    for (int i = 0; i < 4; i++)
#pragma unroll
        for (int j = 0; j < 8; j++) {
            int col = bn + wc + j * 16 + m;
            float dv = dvec[col];
#pragma unroll
            for (int r = 0; r < 4; r++) {
                int row = bm + wr + i * 16 + q * 4 + r;
                Cout[(size_t)row * 512 + col] =
                    acc[i][j][r] + dv * U[(size_t)row * 512 + col];
            }
        }
}

// ---------------------------------------------------------------------------
// Scan pass 1: local chunk scan, IN-PLACE (writes s_loc over Bu) + ends.
// Thread handles 2 adjacent p's; 16B loads and stores.
// ---------------------------------------------------------------------------
__global__ __launch_bounds__(256) void scan_pass1(
    float4* __restrict__ Bu4, const float2* __restrict__ Abar,
    float2* __restrict__ ends)
{
    int tid = blockIdx.x * 256 + threadIdx.x;   // 0 .. NCH*128-1
    int chunk = tid >> 7;
    int pq = tid & 127;                          // p0 = 2*pq, p1 = 2*pq+1
    float2 A0 = Abar[2 * pq], A1 = Abar[2 * pq + 1];
    float2 s0 = make_float2(0.f, 0.f), s1 = make_float2(0.f, 0.f);
    float4* ptr = Bu4 + (size_t)chunk * CS * 128 + pq;
#pragma unroll 8
    for (int i = 0; i < CS; i++) {
        float4 v = ptr[(size_t)i * 128];
        float sr0 = fmaf(A0.x, s0.x, fmaf(-A0.y, s0.y, v.x));
        float si0 = fmaf(A0.x, s0.y, fmaf(A0.y, s0.x, v.y));
        float sr1 = fmaf(A1.x, s1.x, fmaf(-A1.y, s1.y, v.z));
        float si1 = fmaf(A1.x, s1.y, fmaf(A1.y, s1.x, v.w));
        s0 = make_float2(sr0, si0); s1 = make_float2(sr1, si1);
        ptr[(size_t)i * 128] = make_float4(sr0, si0, sr1, si1);
    }
    ends[(size_t)(2 * pq) * NCH + chunk] = s0;
    ends[(size_t)(2 * pq + 1) * NCH + chunk] = s1;
}

// ---------------------------------------------------------------------------
// Scan pass 2: per-p Kogge-Stone over NCH chunk pairs (A^CS, end) -> carries,
// written chunk-major: carr[chunk][p].
// ---------------------------------------------------------------------------
__global__ __launch_bounds__(1024) void scan_pass2(
    const float2* __restrict__ ends, const float2* __restrict__ Abar,
    float2* __restrict__ carries)
{
    __shared__ float2 sA[NCH];
    __shared__ float2 sB[NCH];
    int p = blockIdx.x;
    int t = threadIdx.x;

    float2 a = Abar[p];
#pragma unroll
    for (int i = 0; i < 5; i++) {    // a^32
        float nr = a.x * a.x - a.y * a.y;
        float ni = 2.f * a.x * a.y;
        a = make_float2(nr, ni);
    }
    float2 A = a;
    float2 bv = ends[(size_t)p * NCH + t];
    sA[t] = A; sB[t] = bv;
    __syncthreads();

    for (int off = 1; off < NCH; off <<= 1) {
        float2 pa, pb;
        bool act = (t >= off);
        if (act) { pa = sA[t - off]; pb = sB[t - off]; }
        __syncthreads();
        if (act) {
            float2 nA = make_float2(A.x * pa.x - A.y * pa.y,
                                    A.x * pa.y + A.y * pa.x);
            float2 nB = make_float2(fmaf(A.x, pb.x, fmaf(-A.y, pb.y, bv.x)),
                                    fmaf(A.x, pb.y, fmaf(A.y, pb.x, bv.y)));
            A = nA; bv = nB;
            sA[t] = A; sB[t] = bv;
        }
        __syncthreads();
    }

    float2 carry = (t == 0) ? make_float2(0.f, 0.f) : sB[t - 1];
    carries[(size_t)t * P_STATE + p] = carry;
}

// ---------------------------------------------------------------------------
extern "C" void kernel_launch(void* const* d_in, const int* in_sizes, int n_in,
                              void* d_out, int out_size, void* d_ws, size_t ws_size,
                              hipStream_t stream) {
    const float* u     = (const float*)d_in[0];   // [L][H]
    const float* lr    = (const float*)d_in[1];   // [P]
    const float* li    = (const float*)d_in[2];   // [P]
    const float* b     = (const float*)d_in[3];   // [P][H][2]
    const float* c     = (const float*)d_in[4];   // [H][P][2]
    const float* dvec  = (const float*)d_in[5];   // [H]
    const float* delta = (const float*)d_in[6];   // [P]
    float* out = (float*)d_out;

    // workspace layout
    char* p = (char*)d_ws;
    float*  Bu      = (float*)p;   p += (size_t)L_SEQ * N2 * 4;        // 64 MiB
    float2* ends    = (float2*)p;  p += (size_t)P_STATE * NCH * 8;     // 2 MiB
    float2* carries = (float2*)p;  p += (size_t)P_STATE * NCH * 8;     // 2 MiB
    ushort* W_hi    = (ushort*)p;  p += (size_t)N2 * H_FEAT * 2;
    ushort* W_lo    = (ushort*)p;  p += (size_t)N2 * H_FEAT * 2;
    ushort* C2_hi   = (ushort*)p;  p += (size_t)H_FEAT * N2 * 2;
    ushort* C2_lo   = (ushort*)p;  p += (size_t)H_FEAT * N2 * 2;
    float2* Abar    = (float2*)p;  p += (size_t)P_STATE * 8;
    float2* Apw     = (float2*)p;  p += (size_t)CS * P_STATE * 8;      // 64 KiB

    // 1. params (+ weight splitting + power table)
    param_kernel<<<(P_STATE * H_FEAT) / 256, 256, 0, stream>>>(
        lr, li, b, c, delta, W_hi, W_lo, C2_hi, C2_lo, Abar, Apw);

    // 2. GEMM1: Bu = u @ W^T   (split-bf16 MFMA)
    {
        dim3 grid(N2 / 256, L_SEQ / 128);
        gemm1<<<grid, 256, 0, stream>>>(u, W_hi, W_lo, Bu);
    }

    // 3. scan: local scan in place + chunk carries (pass3 fused into gemm2)
    scan_pass1<<<NCH * 128 / 256, 256, 0, stream>>>(
        (float4*)Bu, Abar, ends);
    scan_pass2<<<P_STATE, NCH, 0, stream>>>(ends, Abar, carries);

    // 4. GEMM2: out = (s_loc + A^(off+1)*carry) @ C2^T + d*u
    {
        dim3 grid(H_FEAT / 256, L_SEQ / 128);
        gemm2<<<grid, 256, 0, stream>>>(Bu, Apw, carries, C2_hi, C2_lo,
                                        out, u, dvec);
    }
}